// Round 1
// baseline (1011.850 us; speedup 1.0000x reference)
//
#include <hip/hip_runtime.h>
#include <hip/hip_bf16.h>
#include <cstdint>
#include <cstddef>

#define N_NODES 100000
#define E_EDGES 6400000
#define E_TOT   (E_EDGES + N_NODES)
#define IN_CH   128
#define NHID    16          // HEADS*HID
#define NB_SCAN ((N_NODES + 1023) / 1024)   // 98

// ---------------- detection: int64 vs int32 edge_index ----------------
__global__ void k_detect(const int* __restrict__ edge, int* __restrict__ flag) {
    if (blockIdx.x == 0 && threadIdx.x == 0) {
        int odd_or = 0;
        for (int i = 0; i < 64; i++) odd_or |= edge[2 * i + 1];
        flag[0] = (odd_or == 0) ? 1 : 0;   // 1 => data is int64 little-endian
    }
}

__device__ __forceinline__ int load_src(const int* e, size_t i, int m64) {
    return m64 ? e[2 * i] : e[i];
}
__device__ __forceinline__ int load_dst(const int* e, size_t i, int m64) {
    return m64 ? e[2 * ((size_t)E_EDGES + i)] : e[(size_t)E_EDGES + i];
}

// ---------------- layer-1 node features: h1 = x@W1, alpha pairs -------
__global__ __launch_bounds__(256) void k_gemm1(
        const float* __restrict__ x, const float* __restrict__ W1,
        const float* __restrict__ a_src1, const float* __restrict__ a_dst1,
        const float* __restrict__ b1,
        float* __restrict__ h1, float* __restrict__ alpha1) {
    __shared__ __align__(16) float sW[IN_CH * NHID];   // 8 KB
    __shared__ __align__(16) float sx[16][132];        // padded stride
    __shared__ float sh[16][17];
    int t = threadIdx.x;
    int r = t >> 4, c = t & 15;
    int row = blockIdx.x * 16 + r;

    const float4* W4 = (const float4*)W1;
    ((float4*)sW)[t] = W4[t];
    ((float4*)sW)[t + 256] = W4[t + 256];

    if (row < N_NODES) {
        const float4* xr = (const float4*)(x + (size_t)row * IN_CH);
        float4 v0 = xr[c];
        float4 v1 = xr[c + 16];
        *(float4*)&sx[r][4 * c] = v0;
        *(float4*)&sx[r][64 + 4 * c] = v1;
    }
    __syncthreads();

    float acc = 0.f;
    if (row < N_NODES) {
        #pragma unroll 16
        for (int k = 0; k < IN_CH; k++) acc = fmaf(sx[r][k], sW[k * NHID + c], acc);
        acc += b1[c];
        h1[(size_t)row * NHID + c] = acc;
    }
    sh[r][c] = acc;
    __syncthreads();

    if (row < N_NODES && c < 4) {
        int h = c & 1;
        const float* av = (c >= 2) ? a_dst1 : a_src1;
        float s = 0.f;
        #pragma unroll
        for (int q = 0; q < 8; q++) s = fmaf(sh[r][h * 8 + q], av[h * 8 + q], s);
        alpha1[(size_t)row * 4 + c] = s;   // [as0, as1, ad0, ad1]
    }
}

// ---------------- CSR build ----------------
__global__ __launch_bounds__(256) void k_hist(const int* __restrict__ edge,
                                              const int* __restrict__ flag,
                                              int* __restrict__ counts) {
    int m64 = flag[0];
    size_t stride = (size_t)gridDim.x * blockDim.x;
    for (size_t i = (size_t)blockIdx.x * blockDim.x + threadIdx.x; i < E_TOT; i += stride) {
        int d = (i < E_EDGES) ? load_dst(edge, i, m64) : (int)(i - E_EDGES);
        atomicAdd(&counts[d], 1);
    }
}

__global__ __launch_bounds__(256) void k_scan1(const int* __restrict__ counts,
                                               int* __restrict__ offs,
                                               int* __restrict__ bsums) {
    __shared__ int sd[256];
    int t = threadIdx.x;
    int base = blockIdx.x * 1024 + t * 4;
    int v[4];
    #pragma unroll
    for (int q = 0; q < 4; q++) v[q] = (base + q < N_NODES) ? counts[base + q] : 0;
    int tsum = v[0] + v[1] + v[2] + v[3];
    sd[t] = tsum;
    __syncthreads();
    for (int ofs = 1; ofs < 256; ofs <<= 1) {
        int xv = sd[t];
        int yv = (t >= ofs) ? sd[t - ofs] : 0;
        __syncthreads();
        sd[t] = xv + yv;
        __syncthreads();
    }
    int run = sd[t] - tsum;   // exclusive prefix for this thread
    #pragma unroll
    for (int q = 0; q < 4; q++) {
        if (base + q < N_NODES) offs[base + q] = run;
        run += v[q];
    }
    if (t == 255) bsums[blockIdx.x] = sd[255];
}

__global__ void k_scan2(int* __restrict__ bsums) {
    __shared__ int sd[128];
    int t = threadIdx.x;
    int v = (t < NB_SCAN) ? bsums[t] : 0;
    sd[t] = v;
    __syncthreads();
    for (int ofs = 1; ofs < 128; ofs <<= 1) {
        int xv = sd[t];
        int yv = (t >= ofs) ? sd[t - ofs] : 0;
        __syncthreads();
        sd[t] = xv + yv;
        __syncthreads();
    }
    if (t < NB_SCAN) bsums[t] = sd[t] - v;   // exclusive
}

__global__ __launch_bounds__(256) void k_scan3(int* __restrict__ offs,
                                               const int* __restrict__ bsums,
                                               int* __restrict__ cursor) {
    int add = bsums[blockIdx.x];
    int base = blockIdx.x * 1024 + threadIdx.x * 4;
    #pragma unroll
    for (int q = 0; q < 4; q++) {
        int i = base + q;
        if (i < N_NODES) {
            int o = offs[i] + add;
            offs[i] = o;
            cursor[i] = o;
        }
    }
    if (blockIdx.x == 0 && threadIdx.x == 0) offs[N_NODES] = E_TOT;
}

__global__ __launch_bounds__(256) void k_scatter(const int* __restrict__ edge,
                                                 const int* __restrict__ flag,
                                                 int* __restrict__ cursor,
                                                 int* __restrict__ csr) {
    int m64 = flag[0];
    size_t stride = (size_t)gridDim.x * blockDim.x;
    for (size_t i = (size_t)blockIdx.x * blockDim.x + threadIdx.x; i < E_TOT; i += stride) {
        int s, d;
        if (i < E_EDGES) { s = load_src(edge, i, m64); d = load_dst(edge, i, m64); }
        else             { s = d = (int)(i - E_EDGES); }
        int pos = atomicAdd(&cursor[d], 1);
        csr[pos] = s;
    }
}

// ---------------- layer-1 edge pass (fused softmax + aggregate + ReLU + @W2)
__global__ __launch_bounds__(256) void k_edge1(
        const int* __restrict__ offs, const int* __restrict__ csr,
        const float* __restrict__ h1, const float* __restrict__ alpha1,
        const float* __restrict__ b1, const float* __restrict__ W2,
        float* __restrict__ h2out) {
    int t = threadIdx.x;
    int g = t >> 4, lane = t & 15;
    int d = blockIdx.x * 16 + g;
    if (d >= N_NODES) return;

    const float2* a2 = (const float2*)alpha1;
    float2 adp = a2[(size_t)d * 2 + 1];          // (ad0, ad1)
    int beg = offs[d], end = offs[d + 1];

    float acc = 0.f, den0 = 0.f, den1 = 0.f;
    int s_next = csr[beg];
    for (int e = beg; e < end; e++) {
        int s = s_next;
        if (e + 1 < end) s_next = csr[e + 1];
        float2 asp = a2[(size_t)s * 2];          // (as0, as1)
        float a0 = asp.x + adp.x; a0 = (a0 > 0.f) ? a0 : 0.2f * a0;
        float a1 = asp.y + adp.y; a1 = (a1 > 0.f) ? a1 : 0.2f * a1;
        float p0 = __expf(a0), p1 = __expf(a1);
        float hv = h1[(size_t)s * NHID + lane];  // coalesced 64B line
        acc = fmaf((lane < 8) ? p0 : p1, hv, acc);
        den0 += p0; den1 += p1;
    }
    float den = (lane < 8) ? den0 : den1;
    float o = acc / (den + 1e-16f) + b1[lane];
    o = (o > 0.f) ? o : 0.f;                     // ReLU
    // fused h2 = relu(out) @ W2   (16 -> 1)
    float v = o * W2[lane];
    v += __shfl_xor(v, 1, 64);
    v += __shfl_xor(v, 2, 64);
    v += __shfl_xor(v, 4, 64);
    v += __shfl_xor(v, 8, 64);
    if (lane == 0) h2out[d] = v;
}

// ---------------- layer-2 edge pass ----------------
__global__ __launch_bounds__(256) void k_edge2(
        const int* __restrict__ offs, const int* __restrict__ csr,
        const float* __restrict__ h2,
        const float* __restrict__ a_src2, const float* __restrict__ a_dst2,
        const float* __restrict__ b2, float* __restrict__ out) {
    int t = threadIdx.x;
    int g = t >> 4, lane = t & 15;
    int d = blockIdx.x * 16 + g;
    if (d >= N_NODES) return;

    float as2 = a_src2[0], ad2 = a_dst2[0];
    float hd = h2[d];
    float adv = hd * ad2;
    int beg = offs[d], end = offs[d + 1];

    float den = 0.f, acc = 0.f;
    for (int e = beg + lane; e < end; e += 16) {
        float hs = h2[csr[e]];
        float a = fmaf(hs, as2, adv);
        a = (a > 0.f) ? a : 0.2f * a;
        float p = __expf(a);
        den += p;
        acc = fmaf(p, hs, acc);
    }
    #pragma unroll
    for (int m = 1; m < 16; m <<= 1) {
        den += __shfl_xor(den, m, 64);
        acc += __shfl_xor(acc, m, 64);
    }
    if (lane == 0) out[d] = acc / (den + 1e-16f) + b2[0];
}

// ---------------- launch ----------------
extern "C" void kernel_launch(void* const* d_in, const int* in_sizes, int n_in,
                              void* d_out, int out_size, void* d_ws, size_t ws_size,
                              hipStream_t stream) {
    const float* x      = (const float*)d_in[0];
    const int*   edge   = (const int*)  d_in[1];
    const float* W1     = (const float*)d_in[2];
    const float* a_src1 = (const float*)d_in[3];
    const float* a_dst1 = (const float*)d_in[4];
    const float* b1     = (const float*)d_in[5];
    const float* W2     = (const float*)d_in[6];
    const float* a_src2 = (const float*)d_in[7];
    const float* a_dst2 = (const float*)d_in[8];
    const float* b2     = (const float*)d_in[9];

    constexpr size_t A = 256;
    auto al = [](size_t b) { return (b + A - 1) / A * A; };
    char* ws = (char*)d_ws;
    size_t off = 0;
    int*   counts = (int*)(ws + off); off += al((size_t)N_NODES * 4);
    int*   offs   = (int*)(ws + off); off += al((size_t)(N_NODES + 1) * 4);
    int*   cursor = (int*)(ws + off); off += al((size_t)N_NODES * 4);
    int*   bsums  = (int*)(ws + off); off += al(256 * 4);
    int*   flag   = (int*)(ws + off); off += al(256);
    int*   csr    = (int*)(ws + off); off += al((size_t)E_TOT * 4);
    float* h1     = (float*)(ws + off); off += al((size_t)N_NODES * NHID * 4);
    float* alpha1 = (float*)(ws + off); off += al((size_t)N_NODES * 4 * 4);
    float* h2     = (float*)(ws + off); off += al((size_t)N_NODES * 4);
    (void)ws_size; (void)in_sizes; (void)n_in; (void)out_size;

    hipMemsetAsync(counts, 0, (size_t)N_NODES * 4, stream);

    k_detect<<<1, 64, 0, stream>>>(edge, flag);
    k_gemm1<<<(N_NODES + 15) / 16, 256, 0, stream>>>(x, W1, a_src1, a_dst1, b1, h1, alpha1);
    k_hist<<<2048, 256, 0, stream>>>(edge, flag, counts);
    k_scan1<<<NB_SCAN, 256, 0, stream>>>(counts, offs, bsums);
    k_scan2<<<1, 128, 0, stream>>>(bsums);
    k_scan3<<<NB_SCAN, 256, 0, stream>>>(offs, bsums, cursor);
    k_scatter<<<2048, 256, 0, stream>>>(edge, flag, cursor, csr);
    k_edge1<<<(N_NODES + 15) / 16, 256, 0, stream>>>(offs, csr, h1, alpha1, b1, W2, h2);
    k_edge2<<<(N_NODES + 15) / 16, 256, 0, stream>>>(offs, csr, h2, a_src2, a_dst2, b2,
                                                     (float*)d_out);
}

// Round 2
// 745.494 us; speedup vs baseline: 1.3573x; 1.3573x over previous
//
#include <hip/hip_runtime.h>
#include <hip/hip_bf16.h>
#include <cstdint>
#include <cstddef>

#define N_NODES 100000
#define E_EDGES 6400000
#define E_TOT   (E_EDGES + N_NODES)
#define IN_CH   128
#define NHID    16          // HEADS*HID
#define NB_SCAN ((N_NODES + 1023) / 1024)   // 98
#define NXCD    8
#define NODES_PER_XCD 12500  // N_NODES / NXCD

// ---------------- detection: int64 vs int32 edge_index ----------------
__global__ void k_detect(const int* __restrict__ edge, int* __restrict__ flag) {
    if (blockIdx.x == 0 && threadIdx.x == 0) {
        int odd_or = 0;
        for (int i = 0; i < 64; i++) odd_or |= edge[2 * i + 1];
        flag[0] = (odd_or == 0) ? 1 : 0;   // 1 => data is int64 little-endian
    }
}

__device__ __forceinline__ int load_src(const int* e, size_t i, int m64) {
    return m64 ? e[2 * i] : e[i];
}
__device__ __forceinline__ int load_dst(const int* e, size_t i, int m64) {
    return m64 ? e[2 * ((size_t)E_EDGES + i)] : e[(size_t)E_EDGES + i];
}

// ---------------- layer-1 node features: h1 = x@W1, alpha pairs -------
__global__ __launch_bounds__(256) void k_gemm1(
        const float* __restrict__ x, const float* __restrict__ W1,
        const float* __restrict__ a_src1, const float* __restrict__ a_dst1,
        const float* __restrict__ b1,
        float* __restrict__ h1, float* __restrict__ alpha1) {
    __shared__ __align__(16) float sW[IN_CH * NHID];   // 8 KB
    __shared__ __align__(16) float sx[16][132];        // padded stride
    __shared__ float sh[16][17];
    int t = threadIdx.x;
    int r = t >> 4, c = t & 15;
    int row = blockIdx.x * 16 + r;

    const float4* W4 = (const float4*)W1;
    ((float4*)sW)[t] = W4[t];
    ((float4*)sW)[t + 256] = W4[t + 256];

    if (row < N_NODES) {
        const float4* xr = (const float4*)(x + (size_t)row * IN_CH);
        float4 v0 = xr[c];
        float4 v1 = xr[c + 16];
        *(float4*)&sx[r][4 * c] = v0;
        *(float4*)&sx[r][64 + 4 * c] = v1;
    }
    __syncthreads();

    float acc = 0.f;
    if (row < N_NODES) {
        #pragma unroll 16
        for (int k = 0; k < IN_CH; k++) acc = fmaf(sx[r][k], sW[k * NHID + c], acc);
        acc += b1[c];
        h1[(size_t)row * NHID + c] = acc;
    }
    sh[r][c] = acc;
    __syncthreads();

    if (row < N_NODES && c < 4) {
        int h = c & 1;
        const float* av = (c >= 2) ? a_dst1 : a_src1;
        float s = 0.f;
        #pragma unroll
        for (int q = 0; q < 8; q++) s = fmaf(sh[r][h * 8 + q], av[h * 8 + q], s);
        alpha1[(size_t)row * 4 + c] = s;   // [as0, as1, ad0, ad1]
    }
}

// ---------------- CSR build (XCD-partitioned by dst range) ----------------
// blockIdx % 8 selects the dst range this block is responsible for. On
// MI355X the default dispatch maps blockIdx % 8 -> XCD, so each range's
// counts/cursor/csr window stays resident in ONE XCD's L2 (locality
// heuristic only; correctness does not depend on the mapping).
__global__ __launch_bounds__(256) void k_hist(const int* __restrict__ edge,
                                              const int* __restrict__ flag,
                                              int* __restrict__ counts) {
    int m64 = flag[0];
    int part = blockIdx.x & (NXCD - 1);
    int lo = part * NODES_PER_XCD;
    int hi = lo + NODES_PER_XCD;
    size_t start = (size_t)(blockIdx.x >> 3) * blockDim.x + threadIdx.x;
    size_t stride = (size_t)(gridDim.x >> 3) * blockDim.x;
    for (size_t i = start; i < E_TOT; i += stride) {
        int d = (i < E_EDGES) ? load_dst(edge, i, m64) : (int)(i - E_EDGES);
        if (d >= lo && d < hi) atomicAdd(&counts[d], 1);
    }
}

__global__ __launch_bounds__(256) void k_scan1(const int* __restrict__ counts,
                                               int* __restrict__ offs,
                                               int* __restrict__ bsums) {
    __shared__ int sd[256];
    int t = threadIdx.x;
    int base = blockIdx.x * 1024 + t * 4;
    int v[4];
    #pragma unroll
    for (int q = 0; q < 4; q++) v[q] = (base + q < N_NODES) ? counts[base + q] : 0;
    int tsum = v[0] + v[1] + v[2] + v[3];
    sd[t] = tsum;
    __syncthreads();
    for (int ofs = 1; ofs < 256; ofs <<= 1) {
        int xv = sd[t];
        int yv = (t >= ofs) ? sd[t - ofs] : 0;
        __syncthreads();
        sd[t] = xv + yv;
        __syncthreads();
    }
    int run = sd[t] - tsum;   // exclusive prefix for this thread
    #pragma unroll
    for (int q = 0; q < 4; q++) {
        if (base + q < N_NODES) offs[base + q] = run;
        run += v[q];
    }
    if (t == 255) bsums[blockIdx.x] = sd[255];
}

__global__ void k_scan2(int* __restrict__ bsums) {
    __shared__ int sd[128];
    int t = threadIdx.x;
    int v = (t < NB_SCAN) ? bsums[t] : 0;
    sd[t] = v;
    __syncthreads();
    for (int ofs = 1; ofs < 128; ofs <<= 1) {
        int xv = sd[t];
        int yv = (t >= ofs) ? sd[t - ofs] : 0;
        __syncthreads();
        sd[t] = xv + yv;
        __syncthreads();
    }
    if (t < NB_SCAN) bsums[t] = sd[t] - v;   // exclusive
}

__global__ __launch_bounds__(256) void k_scan3(int* __restrict__ offs,
                                               const int* __restrict__ bsums,
                                               int* __restrict__ cursor) {
    int add = bsums[blockIdx.x];
    int base = blockIdx.x * 1024 + threadIdx.x * 4;
    #pragma unroll
    for (int q = 0; q < 4; q++) {
        int i = base + q;
        if (i < N_NODES) {
            int o = offs[i] + add;
            offs[i] = o;
            cursor[i] = o;
        }
    }
    if (blockIdx.x == 0 && threadIdx.x == 0) offs[N_NODES] = E_TOT;
}

__global__ __launch_bounds__(256) void k_scatter(const int* __restrict__ edge,
                                                 const int* __restrict__ flag,
                                                 int* __restrict__ cursor,
                                                 int* __restrict__ csr) {
    int m64 = flag[0];
    int part = blockIdx.x & (NXCD - 1);
    int lo = part * NODES_PER_XCD;
    int hi = lo + NODES_PER_XCD;
    size_t start = (size_t)(blockIdx.x >> 3) * blockDim.x + threadIdx.x;
    size_t stride = (size_t)(gridDim.x >> 3) * blockDim.x;
    for (size_t i = start; i < E_TOT; i += stride) {
        int d = (i < E_EDGES) ? load_dst(edge, i, m64) : (int)(i - E_EDGES);
        if (d >= lo && d < hi) {
            int s = (i < E_EDGES) ? load_src(edge, i, m64) : d;
            int pos = atomicAdd(&cursor[d], 1);
            csr[pos] = s;
        }
    }
}

// ---------------- layer-1 edge pass (fused softmax + aggregate + ReLU + @W2)
__global__ __launch_bounds__(256) void k_edge1(
        const int* __restrict__ offs, const int* __restrict__ csr,
        const float* __restrict__ h1, const float* __restrict__ alpha1,
        const float* __restrict__ b1, const float* __restrict__ W2,
        float* __restrict__ h2out) {
    int t = threadIdx.x;
    int g = t >> 4, lane = t & 15;
    int d = blockIdx.x * 16 + g;
    if (d >= N_NODES) return;

    const float2* a2 = (const float2*)alpha1;
    float2 adp = a2[(size_t)d * 2 + 1];          // (ad0, ad1)
    int beg = offs[d], end = offs[d + 1];

    float acc = 0.f, den0 = 0.f, den1 = 0.f;
    int s_next = csr[beg];
    for (int e = beg; e < end; e++) {
        int s = s_next;
        if (e + 1 < end) s_next = csr[e + 1];
        float2 asp = a2[(size_t)s * 2];          // (as0, as1)
        float a0 = asp.x + adp.x; a0 = (a0 > 0.f) ? a0 : 0.2f * a0;
        float a1 = asp.y + adp.y; a1 = (a1 > 0.f) ? a1 : 0.2f * a1;
        float p0 = __expf(a0), p1 = __expf(a1);
        float hv = h1[(size_t)s * NHID + lane];  // coalesced 64B line
        acc = fmaf((lane < 8) ? p0 : p1, hv, acc);
        den0 += p0; den1 += p1;
    }
    float den = (lane < 8) ? den0 : den1;
    float o = acc / (den + 1e-16f) + b1[lane];
    o = (o > 0.f) ? o : 0.f;                     // ReLU
    // fused h2 = relu(out) @ W2   (16 -> 1)
    float v = o * W2[lane];
    v += __shfl_xor(v, 1, 64);
    v += __shfl_xor(v, 2, 64);
    v += __shfl_xor(v, 4, 64);
    v += __shfl_xor(v, 8, 64);
    if (lane == 0) h2out[d] = v;
}

// ---------------- layer-2 edge pass ----------------
__global__ __launch_bounds__(256) void k_edge2(
        const int* __restrict__ offs, const int* __restrict__ csr,
        const float* __restrict__ h2,
        const float* __restrict__ a_src2, const float* __restrict__ a_dst2,
        const float* __restrict__ b2, float* __restrict__ out) {
    int t = threadIdx.x;
    int g = t >> 4, lane = t & 15;
    int d = blockIdx.x * 16 + g;
    if (d >= N_NODES) return;

    float as2 = a_src2[0], ad2 = a_dst2[0];
    float hd = h2[d];
    float adv = hd * ad2;
    int beg = offs[d], end = offs[d + 1];

    float den = 0.f, acc = 0.f;
    for (int e = beg + lane; e < end; e += 16) {
        float hs = h2[csr[e]];
        float a = fmaf(hs, as2, adv);
        a = (a > 0.f) ? a : 0.2f * a;
        float p = __expf(a);
        den += p;
        acc = fmaf(p, hs, acc);
    }
    #pragma unroll
    for (int m = 1; m < 16; m <<= 1) {
        den += __shfl_xor(den, m, 64);
        acc += __shfl_xor(acc, m, 64);
    }
    if (lane == 0) out[d] = acc / (den + 1e-16f) + b2[0];
}

// ---------------- launch ----------------
extern "C" void kernel_launch(void* const* d_in, const int* in_sizes, int n_in,
                              void* d_out, int out_size, void* d_ws, size_t ws_size,
                              hipStream_t stream) {
    const float* x      = (const float*)d_in[0];
    const int*   edge   = (const int*)  d_in[1];
    const float* W1     = (const float*)d_in[2];
    const float* a_src1 = (const float*)d_in[3];
    const float* a_dst1 = (const float*)d_in[4];
    const float* b1     = (const float*)d_in[5];
    const float* W2     = (const float*)d_in[6];
    const float* a_src2 = (const float*)d_in[7];
    const float* a_dst2 = (const float*)d_in[8];
    const float* b2     = (const float*)d_in[9];

    constexpr size_t A = 256;
    auto al = [](size_t b) { return (b + A - 1) / A * A; };
    char* ws = (char*)d_ws;
    size_t off = 0;
    int*   counts = (int*)(ws + off); off += al((size_t)N_NODES * 4);
    int*   offs   = (int*)(ws + off); off += al((size_t)(N_NODES + 1) * 4);
    int*   cursor = (int*)(ws + off); off += al((size_t)N_NODES * 4);
    int*   bsums  = (int*)(ws + off); off += al(256 * 4);
    int*   flag   = (int*)(ws + off); off += al(256);
    int*   csr    = (int*)(ws + off); off += al((size_t)E_TOT * 4);
    float* h1     = (float*)(ws + off); off += al((size_t)N_NODES * NHID * 4);
    float* alpha1 = (float*)(ws + off); off += al((size_t)N_NODES * 4 * 4);
    float* h2     = (float*)(ws + off); off += al((size_t)N_NODES * 4);
    (void)ws_size; (void)in_sizes; (void)n_in; (void)out_size;

    hipMemsetAsync(counts, 0, (size_t)N_NODES * 4, stream);

    k_detect<<<1, 64, 0, stream>>>(edge, flag);
    k_gemm1<<<(N_NODES + 15) / 16, 256, 0, stream>>>(x, W1, a_src1, a_dst1, b1, h1, alpha1);
    k_hist<<<2048, 256, 0, stream>>>(edge, flag, counts);
    k_scan1<<<NB_SCAN, 256, 0, stream>>>(counts, offs, bsums);
    k_scan2<<<1, 128, 0, stream>>>(bsums);
    k_scan3<<<NB_SCAN, 256, 0, stream>>>(offs, bsums, cursor);
    k_scatter<<<2048, 256, 0, stream>>>(edge, flag, cursor, csr);
    k_edge1<<<(N_NODES + 15) / 16, 256, 0, stream>>>(offs, csr, h1, alpha1, b1, W2, h2);
    k_edge2<<<(N_NODES + 15) / 16, 256, 0, stream>>>(offs, csr, h2, a_src2, a_dst2, b2,
                                                     (float*)d_out);
}